// Round 1
// 1833.810 us; speedup vs baseline: 1.1101x; 1.1101x over previous
//
#include <hip/hip_runtime.h>

#define Bb 8
#define Nn 2500
#define Ee 100
#define Ff 50
#define Yy 8922
#define Kk 9
#define YT 10          // y-rows per block in attention kernel (1 wave per row)
#define NCH 625        // Nn/4 float4 chunks

// ---------------------------------------------------------------------------
// Kernel 1: embedding lookup + conv1d (SAME, K=9) + tanh
// writes h[b][n][f] and h_t[b][f][n]            (unchanged from baseline)
// ---------------------------------------------------------------------------
__global__ __launch_bounds__(256)
void conv_kernel(const int* __restrict__ x, const float* __restrict__ embW,
                 const float* __restrict__ convW, const float* __restrict__ convB,
                 float* __restrict__ h, float* __restrict__ h_t)
{
    __shared__ __align__(16) float emb_s[72 * 101];   // 72 rows (64 + 8 halo), pad 101
    __shared__ __align__(16) float w_s[100 * 64];     // [e][4 groups x 16 slots]

    const int b  = blockIdx.y;
    const int n0 = blockIdx.x * 64;
    const int t  = threadIdx.x;

    for (int idx = t; idx < 72 * Ee; idx += 256) {
        int r = idx / Ee, c = idx - r * Ee;
        int n = n0 - 4 + r;
        float v = 0.0f;
        if (n >= 0 && n < Nn) v = embW[(size_t)x[b * Nn + n] * Ee + c];
        emb_s[r * 101 + c] = v;
    }

    const int nl = t & 63;   // n within tile
    const int g  = t >> 6;   // f-group: f = 13*g + j
    float acc[13];
#pragma unroll
    for (int j = 0; j < 13; ++j) acc[j] = 0.0f;

    for (int k = 0; k < Kk; ++k) {
        __syncthreads();
        for (int idx = t; idx < 100 * 64; idx += 256) {
            int e = idx >> 6, slot = idx & 63;
            int g2 = slot >> 4, j2 = slot & 15;
            int f2 = g2 * 13 + j2;
            float v = 0.0f;
            if (j2 < 13 && f2 < Ff) v = convW[(f2 * Ee + e) * Kk + k];
            w_s[idx] = v;
        }
        __syncthreads();
        const float* er    = &emb_s[(nl + k) * 101];
        const float* wbase = &w_s[g * 16];
        for (int e = 0; e < Ee; ++e) {
            float ev = er[e];
            const float* wr = wbase + e * 64;
            float4 w0 = *(const float4*)(wr);
            float4 w1 = *(const float4*)(wr + 4);
            float4 w2 = *(const float4*)(wr + 8);
            float  wc = wr[12];
            acc[0]  += ev * w0.x; acc[1]  += ev * w0.y; acc[2]  += ev * w0.z; acc[3]  += ev * w0.w;
            acc[4]  += ev * w1.x; acc[5]  += ev * w1.y; acc[6]  += ev * w1.z; acc[7]  += ev * w1.w;
            acc[8]  += ev * w2.x; acc[9]  += ev * w2.y; acc[10] += ev * w2.z; acc[11] += ev * w2.w;
            acc[12] += ev * wc;
        }
    }

    const int n = n0 + nl;
    if (n < Nn) {
#pragma unroll
        for (int j = 0; j < 13; ++j) {
            int f = g * 13 + j;
            if (f < Ff) {
                float v = tanhf(acc[j] + convB[f]);
                h  [((size_t)b * Nn + n) * Ff + f] = v;
                h_t[((size_t)b * Ff + f) * Nn + n] = v;
            }
        }
    }
}

// ---------------------------------------------------------------------------
// Kernel 2: per-label attention, YT=10 rows/block, 640 threads (10 waves)
//   P1: scores into LDS, register-blocked over all 10 y-rows per n-chunk
//   P2: softmax per row (wave-owned), 1 exp/element, alpha -> LDS + global
//   P3: pool m[y][f] with f-lane mapping, alpha broadcast from LDS
//   P4: cross-strip reduce, logits, sigmoid
// ---------------------------------------------------------------------------
#define FMA4(A, HV, U) { A.x += HV.x*(U); A.y += HV.y*(U); A.z += HV.z*(U); A.w += HV.w*(U); }

__global__ __launch_bounds__(640)
void attn_kernel(const float* __restrict__ h, const float* __restrict__ h_t,
                 const float* __restrict__ U_w, const float* __restrict__ fin,
                 const float* __restrict__ finb, float* __restrict__ out)
{
    __shared__ __align__(16) float sc[YT * Nn];           // 100000 B score/alpha rows
    __shared__ __align__(16) float U_s[Ff * 12];          // [f][j], stride 12 (48B, f4-aligned)
    __shared__ __align__(16) float m_buf[YT * YT * 64];   // [strip][y][lane] partials, 25600 B

    const int b  = blockIdx.y;
    const int y0 = blockIdx.x * YT;
    const int t  = threadIdx.x;
    const int l  = t & 63;
    const int w  = t >> 6;          // wave id 0..9

    for (int idx = t; idx < Ff * YT; idx += 640) {
        int f = idx / YT, j = idx - f * YT;
        int y = y0 + j;
        U_s[f * 12 + j] = (y < Yy) ? U_w[y * Ff + f] : 0.0f;
    }
    __syncthreads();

    // ---- Phase 1: scores[j][n4..n4+3] for all 10 j, one n-chunk per thread ----
    if (t < NCH) {
        const int n4 = t * 4;
        const float* hp = h_t + (size_t)b * Ff * Nn + n4;
        float4 a[YT];
#pragma unroll
        for (int j = 0; j < YT; ++j) a[j] = make_float4(0.f, 0.f, 0.f, 0.f);
#pragma unroll 2
        for (int f = 0; f < Ff; ++f) {
            float4 hv = *(const float4*)(hp + (size_t)f * Nn);
            const float* ur = &U_s[f * 12];
            float4 u0 = *(const float4*)(ur);
            float4 u1 = *(const float4*)(ur + 4);
            float2 u2 = *(const float2*)(ur + 8);
            FMA4(a[0], hv, u0.x); FMA4(a[1], hv, u0.y); FMA4(a[2], hv, u0.z); FMA4(a[3], hv, u0.w);
            FMA4(a[4], hv, u1.x); FMA4(a[5], hv, u1.y); FMA4(a[6], hv, u1.z); FMA4(a[7], hv, u1.w);
            FMA4(a[8], hv, u2.x); FMA4(a[9], hv, u2.y);
        }
#pragma unroll
        for (int j = 0; j < YT; ++j)
            *(float4*)&sc[j * Nn + n4] = a[j];
    }
    __syncthreads();

    // ---- Phase 2: softmax of row w (one wave per row), alpha -> sc + global ----
    {
        const int y = y0 + w;
        const bool valid = (y < Yy);
        float4 v[10];
        float M = -3.0e38f;
#pragma unroll
        for (int i = 0; i < 10; ++i) {
            int c = l + 64 * i;
            if (c < NCH) {
                v[i] = *(const float4*)&sc[w * Nn + c * 4];
                M = fmaxf(M, fmaxf(fmaxf(v[i].x, v[i].y), fmaxf(v[i].z, v[i].w)));
            }
        }
#pragma unroll
        for (int o = 32; o > 0; o >>= 1) M = fmaxf(M, __shfl_xor(M, o));
        float S = 0.0f;
#pragma unroll
        for (int i = 0; i < 10; ++i) {
            int c = l + 64 * i;
            if (c < NCH) {
                v[i].x = __expf(v[i].x - M); v[i].y = __expf(v[i].y - M);
                v[i].z = __expf(v[i].z - M); v[i].w = __expf(v[i].w - M);
                S += (v[i].x + v[i].y) + (v[i].z + v[i].w);
            }
        }
#pragma unroll
        for (int o = 32; o > 0; o >>= 1) S += __shfl_xor(S, o);
        const float inv = 1.0f / S;
        float* ag = out + (size_t)Bb * Yy + 1 + ((size_t)b * Yy + y) * (size_t)Nn;
#pragma unroll
        for (int i = 0; i < 10; ++i) {
            int c = l + 64 * i;
            if (c < NCH) {
                float4 av;
                av.x = v[i].x * inv; av.y = v[i].y * inv;
                av.z = v[i].z * inv; av.w = v[i].w * inv;
                *(float4*)&sc[w * Nn + c * 4] = av;
                if (valid) {
                    const int n = c * 4;
                    ag[n] = av.x; ag[n + 1] = av.y; ag[n + 2] = av.z; ag[n + 3] = av.w;
                }
            }
        }
    }
    __syncthreads();

    // ---- Phase 3: m[j][f] partials; lane = f, wave = n-strip ----
    const float* hbn = h + (size_t)b * Nn * Ff;
    float m[YT];
#pragma unroll
    for (int j = 0; j < YT; ++j) m[j] = 0.0f;
    if (l < Ff) {
#pragma unroll 2
        for (int qi = w; qi < NCH; qi += YT) {
            const int n4 = qi * 4;
            const float* hp = hbn + (size_t)n4 * Ff + l;
            float h0 = hp[0], h1 = hp[Ff], h2 = hp[2 * Ff], h3 = hp[3 * Ff];
#pragma unroll
            for (int j = 0; j < YT; ++j) {
                float4 av = *(const float4*)&sc[j * Nn + n4];
                m[j] += av.x * h0 + av.y * h1 + av.z * h2 + av.w * h3;
            }
        }
    }
#pragma unroll
    for (int j = 0; j < YT; ++j) m_buf[(w * YT + j) * 64 + l] = m[j];
    __syncthreads();

    // ---- Phase 4: reduce strips, logits, sigmoid ----
    {
        float s = 0.0f;
#pragma unroll
        for (int ww = 0; ww < YT; ++ww) s += m_buf[(ww * YT + w) * 64 + l];
        const int y = y0 + w;
        float p = (l < Ff && y < Yy) ? s * fin[y * Ff + l] : 0.0f;
#pragma unroll
        for (int o = 32; o > 0; o >>= 1) p += __shfl_xor(p, o);
        if (l == 0 && y < Yy) {
            out[b * Yy + y] = 1.0f / (1.0f + __expf(-(p + finb[y])));
        }
    }
}

// ---------------------------------------------------------------------------
// Kernel 3: BCE loss (mean) over yhat (already in out[0..B*Y)) vs target
// ---------------------------------------------------------------------------
__global__ __launch_bounds__(1024)
void loss_kernel(const float* __restrict__ target, float* __restrict__ out)
{
    __shared__ float red[16];
    const int t = threadIdx.x;
    float acc = 0.0f;
    for (int i = t; i < Bb * Yy; i += 1024) {
        float p = out[i];
        p = fminf(fmaxf(p, 1e-7f), 1.0f - 1e-7f);
        float tg = target[i];
        acc += tg * logf(p) + (1.0f - tg) * log1pf(-p);
    }
#pragma unroll
    for (int o = 32; o > 0; o >>= 1) acc += __shfl_xor(acc, o);
    if ((t & 63) == 0) red[t >> 6] = acc;
    __syncthreads();
    if (t == 0) {
        float s = 0.0f;
#pragma unroll
        for (int i = 0; i < 16; ++i) s += red[i];
        out[Bb * Yy] = -s / (float)(Bb * Yy);
    }
}

// ---------------------------------------------------------------------------
extern "C" void kernel_launch(void* const* d_in, const int* in_sizes, int n_in,
                              void* d_out, int out_size, void* d_ws, size_t ws_size,
                              hipStream_t stream)
{
    const int*   x      = (const int*)  d_in[0];
    const float* target = (const float*)d_in[1];
    const float* embW   = (const float*)d_in[2];
    const float* convW  = (const float*)d_in[3];
    const float* convB  = (const float*)d_in[4];
    const float* U_w    = (const float*)d_in[5];
    const float* fin    = (const float*)d_in[6];
    const float* finb   = (const float*)d_in[7];
    float* out = (float*)d_out;
    float* h   = (float*)d_ws;                                    // 4 MB: h[b][n][f]
    float* h_t = (float*)((char*)d_ws + (size_t)4 * 1024 * 1024); // 4 MB: h_t[b][f][n]

    dim3 g1((Nn + 63) / 64, Bb);
    conv_kernel<<<g1, dim3(256), 0, stream>>>(x, embW, convW, convB, h, h_t);

    dim3 g2((Yy + YT - 1) / YT, Bb);
    attn_kernel<<<g2, dim3(640), 0, stream>>>(h, h_t, U_w, fin, finb, out);

    loss_kernel<<<dim3(1), dim3(1024), 0, stream>>>(target, out);
}